// Round 8
// baseline (16462.869 us; speedup 1.0000x reference)
//
#include <hip/hip_runtime.h>
#include <stdint.h>

typedef short short8 __attribute__((ext_vector_type(8)));
typedef float f32x4 __attribute__((ext_vector_type(4)));
typedef float f32x16 __attribute__((ext_vector_type(16)));

#define N_NODES 500
#define HGC 16
#define DH 512
#define T_STEPS 64
#define NB 32
#define F_IN 8
#define DSTEPS 16
#define E_EDGES 16000
#define E_TOT 16500
#define NH 8000          // N*HG
#define G3 1536          // 3*D
#define BT 2048          // B*T
#define DKC 10           // decoder K-split (800 k / chunk = 50 nodes)
#define DNT 48           // decoder ntiles (32 cols each)
#define DBLK 480         // 48 x 10 persistent blocks

__device__ __forceinline__ unsigned short f2bf(float x) {
  unsigned int u = __float_as_uint(x);
  u = (u + 0x7fffu + ((u >> 16) & 1u)) >> 16;
  return (unsigned short)u;
}

__device__ __forceinline__ void gl_lds16(const void* g, void* l) {
  __builtin_amdgcn_global_load_lds((const __attribute__((address_space(1))) void*)g,
                                   (__attribute__((address_space(3))) void*)l, 16, 0, 0);
}

__device__ __forceinline__ float sigm(float x) { return 1.f / (1.f + __expf(-x)); }

// ---------------- graph prep ----------------
__global__ void k_deg_init(int* deg) {
  int t = blockIdx.x * blockDim.x + threadIdx.x;
  if (t < N_NODES) deg[t] = 1;  // self loop
}

__global__ void k_deg_count(const int* __restrict__ ei, int* deg) {
  int t = blockIdx.x * blockDim.x + threadIdx.x;
  if (t < E_EDGES) atomicAdd(&deg[ei[E_EDGES + t]], 1);
}

__global__ void k_scan(const int* __restrict__ deg, float* dinv, int* rowptr, int* cursor) {
  __shared__ int s[512];
  int t = threadIdx.x;
  int v = (t < N_NODES) ? deg[t] : 0;
  s[t] = v;
  __syncthreads();
  for (int off = 1; off < 512; off <<= 1) {
    int add = (t >= off) ? s[t - off] : 0;
    __syncthreads();
    s[t] += add;
    __syncthreads();
  }
  if (t < N_NODES) {
    int excl = s[t] - v;
    rowptr[t] = excl;
    cursor[t] = excl;
    dinv[t] = rsqrtf((float)v);
  }
  if (t == 0) rowptr[N_NODES] = s[511];
}

__global__ void k_scatter(const int* __restrict__ ei, const float* __restrict__ dinv,
                          int* cursor, int* col, float* nrm) {
  int t = blockIdx.x * blockDim.x + threadIdx.x;
  if (t >= E_TOT) return;
  int s_, d_;
  if (t < E_EDGES) { s_ = ei[t]; d_ = ei[E_EDGES + t]; }
  else { s_ = d_ = t - E_EDGES; }
  int pos = atomicAdd(&cursor[d_], 1);
  col[pos] = s_;
  nrm[pos] = dinv[s_] * dinv[d_];
}

// ---------------- f32 -> bf16 bulk convert ----------------
__global__ void k_f2bf4(const float* __restrict__ src, unsigned short* __restrict__ dst, int n4) {
  int i = blockIdx.x * blockDim.x + threadIdx.x;
  if (i >= n4) return;
  float4 v = ((const float4*)src)[i];
  ushort4 o;
  o.x = f2bf(v.x); o.y = f2bf(v.y); o.z = f2bf(v.z); o.w = f2bf(v.w);
  ((ushort4*)dst)[i] = o;
}

// ---------------- repack dWih f32 -> per-block LDS blobs (bf16), fused convert ----------------
// blob = ntile*10+kc : [50 nodes][32 cols][16 c] bf16  (1024 B per node chunk)
__global__ __launch_bounds__(256) void k_repack(const float* __restrict__ dWih,
                                                unsigned short* __restrict__ wihDp) {
  int i = blockIdx.x * 256 + threadIdx.x;   // 768000 total
  if (i >= DBLK * 50 * 32) return;
  int blob = i / 1600, r = i - blob * 1600;
  int nd = r >> 5, col = r & 31;
  int ntile = blob / DKC, kc = blob - ntile * DKC;
  const float* src = dWih + (size_t)(ntile * 32 + col) * NH + kc * 800 + nd * 16;
  short8 lo, hi;
#pragma unroll
  for (int c = 0; c < 8; ++c) {
    lo[c] = (short)f2bf(src[c]);
    hi[c] = (short)f2bf(src[c + 8]);
  }
  unsigned short* dst = wihDp + (size_t)blob * 25600 + nd * 512 + col * 16;
  *(short8*)dst = lo;
  *(short8*)(dst + 8) = hi;
}

// ---------------- x (2048,500,8) f32 -> xT2 (16384, 512) bf16 (zero-padded cols) ----------------
__global__ __launch_bounds__(256) void k_transpose(const float* __restrict__ x,
                                                   unsigned short* __restrict__ xT2) {
  __shared__ float xs[N_NODES * 9];
  int g = blockIdx.x, t = threadIdx.x;
  const float4* xg = (const float4*)(x + (size_t)g * (N_NODES * F_IN));
  for (int i = t; i < N_NODES * 2; i += 256) {
    float4 v = xg[i];
    int n = i >> 1, fh = (i & 1) * 4;
    float* d = &xs[n * 9 + fh];
    d[0] = v.x; d[1] = v.y; d[2] = v.z; d[3] = v.w;
  }
  __syncthreads();
  int f = t >> 5, u = t & 31;
  short8 lo, hi;
#pragma unroll
  for (int j = 0; j < 8; ++j) {
    int n0 = u * 16 + j, n1 = n0 + 8;
    lo[j] = (short)((n0 < N_NODES) ? f2bf(xs[n0 * 9 + f]) : 0);
    hi[j] = (short)((n1 < N_NODES) ? f2bf(xs[n1 * 9 + f]) : 0);
  }
  unsigned short* dst = xT2 + (size_t)(g * 8 + f) * 512 + u * 16;
  *(short8*)dst = lo;
  *(short8*)(dst + 8) = hi;
}

// ---------------- densify Ahat rows (by dst) -> (512, 512) bf16 ----------------
__global__ __launch_bounds__(256) void k_densify(const int* __restrict__ rowptr,
                                                 const int* __restrict__ col,
                                                 const float* __restrict__ nrm,
                                                 unsigned short* __restrict__ AhatD) {
  __shared__ float row[512];
  int n = blockIdx.x, t = threadIdx.x;
  row[t] = 0.f; row[t + 256] = 0.f;
  __syncthreads();
  if (n < N_NODES) {
    int e1 = rowptr[n + 1];
    for (int e = rowptr[n] + t; e < e1; e += 256) atomicAdd(&row[col[e]], nrm[e]);
  }
  __syncthreads();
  AhatD[n * 512 + t] = f2bf(row[t]);
  AhatD[n * 512 + t + 256] = f2bf(row[t + 256]);
}

// ---------------- agg GEMM: C(16384 gf, 512 n) = xT2 . AhatD^T ; fused W(8->16)+relu -> emb ----------------
__global__ __launch_bounds__(256) void k_gemm_agg(const unsigned short* __restrict__ A,
                                                  const unsigned short* __restrict__ B,
                                                  const float* __restrict__ W,
                                                  const float* __restrict__ bias,
                                                  unsigned short* __restrict__ emb) {
  __shared__ float smem[64 * 129];
  __shared__ float Wsm[F_IN * HGC];
  __shared__ float bsm[HGC];
  unsigned short* As = (unsigned short*)smem;
  unsigned short* Bs = As + 4096;
  int t = threadIdx.x;
  if (t < F_IN * HGC) Wsm[t] = W[t];
  if (t < HGC) bsm[t] = bias[t];
  int m0 = blockIdx.x * 128, n0 = blockIdx.y * 128;
  int wave = t >> 6, lane = t & 63;
  int mh = (wave >> 1) * 64, nh = (wave & 1) * 64;
  int lrow = t >> 2, lslot = t & 3;
  f32x4 acc[4][4];
#pragma unroll
  for (int a = 0; a < 4; ++a)
#pragma unroll
    for (int b = 0; b < 4; ++b) acc[a][b] = (f32x4){0.f, 0.f, 0.f, 0.f};
  const unsigned short* ga0 = A + (size_t)(m0 + lrow) * 512 + lslot * 8;
  const unsigned short* ga1 = A + (size_t)(m0 + 64 + lrow) * 512 + lslot * 8;
  const unsigned short* gb0 = B + (size_t)(n0 + lrow) * 512 + lslot * 8;
  const unsigned short* gb1 = B + (size_t)(n0 + 64 + lrow) * 512 + lslot * 8;
  int rl = lane & 15, ks = lane >> 4;
  for (int kt = 0; kt < 16; ++kt) {
    int k0 = kt * 32;
    gl_lds16(ga0 + k0, &As[t * 8]);
    gl_lds16(ga1 + k0, &As[2048 + t * 8]);
    gl_lds16(gb0 + k0, &Bs[t * 8]);
    gl_lds16(gb1 + k0, &Bs[2048 + t * 8]);
    __syncthreads();
    short8 af[4], bfr[4];
#pragma unroll
    for (int mf = 0; mf < 4; ++mf) af[mf] = *(const short8*)&As[(mh + mf * 16 + rl) * 32 + ks * 8];
#pragma unroll
    for (int nf = 0; nf < 4; ++nf) bfr[nf] = *(const short8*)&Bs[(nh + nf * 16 + rl) * 32 + ks * 8];
#pragma unroll
    for (int mf = 0; mf < 4; ++mf)
#pragma unroll
      for (int nf = 0; nf < 4; ++nf)
        acc[mf][nf] = __builtin_amdgcn_mfma_f32_16x16x32_bf16(af[mf], bfr[nf], acc[mf][nf], 0, 0, 0);
    __syncthreads();
  }
  int rg = lane >> 4;
  for (int p = 0; p < 2; ++p) {
    if ((wave >> 1) == p) {
#pragma unroll
      for (int mf = 0; mf < 4; ++mf)
#pragma unroll
        for (int nf = 0; nf < 4; ++nf)
#pragma unroll
          for (int q = 0; q < 4; ++q)
            smem[(mf * 16 + rg * 4 + q) * 129 + nh + nf * 16 + rl] = acc[mf][nf][q];
    }
    __syncthreads();
    int gl = t >> 5, sub = t & 31;
    int g = blockIdx.x * 16 + p * 8 + gl;
#pragma unroll
    for (int j = 0; j < 4; ++j) {
      int nl = sub + 32 * j, ng = n0 + nl;
      if (ng < N_NODES) {
        float v[8];
#pragma unroll
        for (int f = 0; f < 8; ++f) v[f] = smem[(gl * 8 + f) * 129 + nl];
        short8 o0, o1;
#pragma unroll
        for (int c = 0; c < 8; ++c) {
          float s0 = bsm[c], s1 = bsm[c + 8];
#pragma unroll
          for (int f = 0; f < 8; ++f) {
            s0 += v[f] * Wsm[f * 16 + c];
            s1 += v[f] * Wsm[f * 16 + c + 8];
          }
          o0[c] = (short)f2bf(fmaxf(s0, 0.f));
          o1[c] = (short)f2bf(fmaxf(s1, 0.f));
        }
        unsigned short* dst = emb + (size_t)g * NH + ng * 16;
        *(short8*)dst = o0;
        *(short8*)(dst + 8) = o1;
      }
    }
    __syncthreads();
  }
}

// ---------------- big encoder GEMM: gi = emb(2048x8000) . Wih(1536x8000)^T ----------------
__global__ __launch_bounds__(256) void k_gemm_enc(
    const unsigned short* __restrict__ A, const unsigned short* __restrict__ Bm,
    float* __restrict__ giP2) {
  __shared__ unsigned short As[128 * 32];
  __shared__ unsigned short Bs[64 * 32];
  int t = threadIdx.x;
  int m0 = blockIdx.x * 128, n0 = blockIdx.y * 64;
  int wave = t >> 6, lane = t & 63;
  int mh = (wave >> 1) * 64, nh = (wave & 1) * 32;
  int lrow = t >> 2, lslot = t & 3;
  f32x4 acc[4][2];
#pragma unroll
  for (int a = 0; a < 4; ++a)
#pragma unroll
    for (int b = 0; b < 2; ++b) acc[a][b] = (f32x4){0.f, 0.f, 0.f, 0.f};
  const unsigned short* ga0 = A + (size_t)(m0 + lrow) * NH + lslot * 8;
  const unsigned short* ga1 = A + (size_t)(m0 + 64 + lrow) * NH + lslot * 8;
  const unsigned short* gb0 = Bm + (size_t)(n0 + lrow) * NH + lslot * 8;
  int rl = lane & 15, ks = lane >> 4;
  for (int kt = 0; kt < 250; ++kt) {
    int k0 = kt * 32;
    gl_lds16(ga0 + k0, &As[t * 8]);
    gl_lds16(ga1 + k0, &As[2048 + t * 8]);
    gl_lds16(gb0 + k0, &Bs[t * 8]);
    __syncthreads();
    short8 af[4], bfr[2];
#pragma unroll
    for (int mf = 0; mf < 4; ++mf) af[mf] = *(const short8*)&As[(mh + mf * 16 + rl) * 32 + ks * 8];
#pragma unroll
    for (int nf = 0; nf < 2; ++nf) bfr[nf] = *(const short8*)&Bs[(nh + nf * 16 + rl) * 32 + ks * 8];
#pragma unroll
    for (int mf = 0; mf < 4; ++mf)
#pragma unroll
      for (int nf = 0; nf < 2; ++nf)
        acc[mf][nf] = __builtin_amdgcn_mfma_f32_16x16x32_bf16(af[mf], bfr[nf], acc[mf][nf], 0, 0, 0);
    __syncthreads();
  }
  int rg = lane >> 4;
  int gate = n0 >> 9;
#pragma unroll
  for (int mf = 0; mf < 4; ++mf)
#pragma unroll
    for (int nf = 0; nf < 2; ++nf) {
      int n = n0 + nh + nf * 16 + rl;
      int d = n & 511, blk = d >> 5, cc = d & 31;
#pragma unroll
      for (int q = 0; q < 4; ++q) {
        int m = m0 + mh + mf * 16 + rg * 4 + q;
        int s = m & 63, bb = m >> 6;
        giP2[(size_t)(s * 16 + blk) * 3072 + gate * 1024 + bb * 32 + cc] = acc[mf][nf][q];
      }
    }
}

// ---------------- stage h into XOR-swizzled LDS (encoder) ----------------
__device__ __forceinline__ void stage_hb(const unsigned short* __restrict__ src,
                                         unsigned short* hb, int t) {
  int bw = t >> 3, i8 = t & 7;
  short8 v[8];
#pragma unroll
  for (int i = 0; i < 8; ++i)
    v[i] = *(const short8*)((const char*)src + bw * 1024 + i8 * 128 + i * 16);
#pragma unroll
  for (int i = 0; i < 8; ++i) {
    int kb = i8 * 128 + i * 16;
    *(short8*)((char*)hb + bw * 1024 + (kb ^ ((bw & 15) << 4))) = v[i];
  }
}

// ---------------- persistent encoder scan (R5 structure) ----------------
__global__ __launch_bounds__(256, 1) void k_enc_scan(
    const unsigned short* __restrict__ whhB, const float* __restrict__ giP2,
    const float* __restrict__ bih, const float* __restrict__ bhh,
    float* __restrict__ hF, unsigned short* __restrict__ hbA,
    unsigned short* __restrict__ hbB, int* __restrict__ arr) {
  __shared__ unsigned short hb[32 * 512];
  __shared__ float gh[3 * 1024];
  __shared__ float h32[1024];
  __shared__ float gi_lds[3072];
  int t = threadIdx.x, bid = blockIdx.x;
  int c0 = bid * 32;
  int lane = t & 63, g = t >> 6;
  int b31 = lane & 31, kg = lane >> 5;

  short8 wreg[32];
  if (g < 3) {
    const unsigned short* brow = whhB + (size_t)(g * 512 + c0 + b31) * 512 + kg * 8;
#pragma unroll
    for (int kk = 0; kk < 32; ++kk) wreg[kk] = *(const short8*)(brow + kk * 16);
  }
  for (int i = t; i < 1024; i += 256) h32[i] = 0.f;
  int cc = t & 31, d = c0 + cc;
  float bi_r = bih[d], bi_z = bih[512 + d], bi_n = bih[1024 + d];
  float bh_r = bhh[d], bh_z = bhh[512 + d], bh_n = bhh[1024 + d];
  int asw = (b31 & 15) << 4;
  {
    const float* src0 = giP2 + (size_t)bid * 3072;
#pragma unroll
    for (int i = 0; i < 3; ++i)
      gl_lds16(src0 + i * 1024 + t * 4, &gi_lds[i * 1024 + t * 4]);
  }
  __syncthreads();

  for (int s = 0; s < T_STEPS; ++s) {
    const unsigned short* hbin = (s & 1) ? hbB : hbA;
    unsigned short* hbout = (s & 1) ? hbA : hbB;
    if (s > 0 && t < 64) {
      for (;;) {
        int v = __hip_atomic_load(&arr[t & 15], __ATOMIC_ACQUIRE, __HIP_MEMORY_SCOPE_AGENT);
        if (__all(v >= s)) break;
        __builtin_amdgcn_s_sleep(1);
      }
    }
    __syncthreads();
    stage_hb(hbin, hb, t);
    __syncthreads();
    if (g < 3) {
      f32x16 acc0, acc1;
#pragma unroll
      for (int q = 0; q < 16; ++q) { acc0[q] = 0.f; acc1[q] = 0.f; }
      const char* abase = (const char*)hb + b31 * 1024;
#pragma unroll
      for (int kk = 0; kk < 32; ++kk) {
        int kb = (kk * 32 + kg * 16) ^ asw;
        short8 a = *(const short8*)(abase + kb);
        if (kk & 1) acc1 = __builtin_amdgcn_mfma_f32_32x32x16_bf16(a, wreg[kk], acc1, 0, 0, 0);
        else acc0 = __builtin_amdgcn_mfma_f32_32x32x16_bf16(a, wreg[kk], acc0, 0, 0, 0);
      }
#pragma unroll
      for (int q = 0; q < 16; ++q) {
        int br = (q & 3) + 8 * (q >> 2) + 4 * kg;
        gh[g * 1024 + br * 32 + b31] = acc0[q] + acc1[q];
      }
    }
    __syncthreads();
#pragma unroll
    for (int j = 0; j < 4; ++j) {
      int i = t + 256 * j;
      int b = (t >> 5) + 8 * j;
      float r = sigm(gi_lds[i] + bi_r + gh[i] + bh_r);
      float z = sigm(gi_lds[1024 + i] + bi_z + gh[1024 + i] + bh_z);
      float nn = tanhf(gi_lds[2048 + i] + bi_n + r * (gh[2048 + i] + bh_n));
      float hnew = (1.f - z) * nn + z * h32[i];
      h32[i] = hnew;
      hbout[b * 512 + d] = f2bf(hnew);
    }
    __syncthreads();
    if (g == 3 && s + 1 < T_STEPS) {
      const float* srcn = giP2 + (size_t)((s + 1) * 16 + bid) * 3072;
#pragma unroll
      for (int i = 0; i < 12; ++i)
        gl_lds16(srcn + (i * 64 + lane) * 4, &gi_lds[(i * 64 + lane) * 4]);
    }
    if (t == 0) {
      __threadfence();
      __hip_atomic_store(&arr[bid], s + 1, __ATOMIC_RELEASE, __HIP_MEMORY_SCOPE_AGENT);
    }
  }
#pragma unroll
  for (int j = 0; j < 4; ++j) {
    int i = t + 256 * j;
    int b = (t >> 5) + 8 * j;
    hF[b * 512 + d] = h32[i];
  }
}

// ---------------- persistent decoder v2: weights LDS-resident across all 16 steps ----------------
// 480 blocks x 64 threads. Each block: wihD slice (32 cols x 800 K) in LDS, loaded once.
// Phases per step: P1 gemm(all) -> P2 gru(0..15) -> P3 fc(0..15) -> P4 agg+E8(0..31).
__global__ __launch_bounds__(64, 1) void k_dec_all2(
    const unsigned short* __restrict__ wihDp, const unsigned short* __restrict__ whhB,
    const float* __restrict__ Wd, const float* __restrict__ bd,
    const float* __restrict__ bih, const float* __restrict__ bhh,
    const unsigned short* __restrict__ fcWb, const float* __restrict__ fcb,
    const int* __restrict__ rowptr, const int* __restrict__ colA, const float* __restrict__ nrmA,
    const float* __restrict__ dec0, const float* __restrict__ hF,
    unsigned short* __restrict__ hbX, unsigned short* __restrict__ hbY,
    unsigned short* __restrict__ E8, float* __restrict__ parts,
    float* __restrict__ out, int* __restrict__ flags) {
  __shared__ unsigned short wlds[25600];  // 51200 B persistent weight slice
  __shared__ float orow_s[512];           // P4 scratch
  int bid = blockIdx.x, t = threadIdx.x;
  int b31 = t & 31, kg = t >> 5;
  int ntile = bid / DKC, kc = bid - ntile * DKC;

  // ---- preload weight slice into LDS (once) ----
  {
    const unsigned short* src = wihDp + (size_t)bid * 25600;
    for (int i = 0; i < 50; ++i)
      gl_lds16(src + i * 512 + t * 8, (char*)wlds + i * 1024 + t * 16);
  }

  // per-role persistent registers
  float hreg[16];
  float bihr = 0, bihz = 0, bihn = 0, bhhr = 0, bhhz = 0, bhhn = 0;
  float fb = 0;
  float wd16[16], bd16[16];
  if (bid < 16) {
    int d = bid * 32 + b31;
    bihr = bih[d]; bihz = bih[512 + d]; bihn = bih[1024 + d];
    bhhr = bhh[d]; bhhz = bhh[512 + d]; bhhn = bhh[1024 + d];
#pragma unroll
    for (int q = 0; q < 16; ++q) {
      int br = (q & 3) + 8 * (q >> 2) + 4 * kg;
      hreg[q] = hF[br * 512 + d];
    }
    int n = bid * 32 + b31;
    fb = (n < N_NODES) ? fcb[n] : 0.f;
  }
  if (bid < NB) {
#pragma unroll
    for (int c = 0; c < 16; ++c) { wd16[c] = Wd[c]; bd16[c] = bd[c]; }
  }
  __syncthreads();  // drains weight preload

  // ---- init: E8 from dec0 (blocks 0..31) ----
  if (bid < NB) {
    const float* srcrow = dec0 + bid * N_NODES;
    for (int i = t; i < N_NODES; i += 64) orow_s[i] = srcrow[i];
    __syncthreads();
    for (int n = t; n < N_NODES; n += 64) {
      int e1 = rowptr[n + 1];
      float a = 0.f;
      for (int e = rowptr[n]; e < e1; ++e) a += nrmA[e] * orow_s[colA[e]];
      short8 lo, hi;
#pragma unroll
      for (int c = 0; c < 8; ++c) {
        lo[c] = (short)f2bf(fmaxf(a * wd16[c] + bd16[c], 0.f));
        hi[c] = (short)f2bf(fmaxf(a * wd16[c + 8] + bd16[c + 8], 0.f));
      }
      unsigned short* dst = E8 + (size_t)bid * NH + n * 16;
      *(short8*)dst = lo;
      *(short8*)(dst + 8) = hi;
    }
  }
  if (t == 0) {
    __threadfence();
    __hip_atomic_store(&flags[bid], 1, __ATOMIC_RELEASE, __HIP_MEMORY_SCOPE_AGENT);
  }

  for (int s = 0; s < DSTEPS; ++s) {
    // ---- wait: E8 ready (flags[0..31] >= 4s+1) ----
    {
      int v = 4 * s + 1;
      for (;;) {
        int f = __hip_atomic_load(&flags[t & 31], __ATOMIC_ACQUIRE, __HIP_MEMORY_SCOPE_AGENT);
        if (__all(f >= v)) break;
        __builtin_amdgcn_s_sleep(1);
      }
      __threadfence();
    }
    // ---- P1: parts(ntile,kc) = E8 . Wih_slice^T  (pure GEMM, weights in LDS) ----
    {
      f32x16 acc;
#pragma unroll
      for (int q = 0; q < 16; ++q) acc[q] = 0.f;
      const unsigned short* ea = E8 + (size_t)b31 * NH + kc * 800 + kg * 8;
      const char* wb = (const char*)wlds + b31 * 32 + kg * 16;
#pragma unroll 10
      for (int nd = 0; nd < 50; ++nd) {
        short8 a = *(const short8*)(ea + nd * 16);
        short8 b = *(const short8*)(wb + nd * 1024);
        acc = __builtin_amdgcn_mfma_f32_32x32x16_bf16(a, b, acc, 0, 0, 0);
      }
      float* pp = parts + (size_t)(kc * DNT + ntile) * 1024 + b31;
#pragma unroll
      for (int q = 0; q < 16; ++q) {
        int br = (q & 3) + 8 * (q >> 2) + 4 * kg;
        pp[br * 32] = acc[q];
      }
    }
    if (t == 0) {
      __threadfence();
      __hip_atomic_store(&flags[bid], 4 * s + 2, __ATOMIC_RELEASE, __HIP_MEMORY_SCOPE_AGENT);
    }

    if (bid < 16) {
      // ---- wait: all 480 P1 done ----
      {
        int v = 4 * s + 2;
        for (;;) {
          bool ok = true;
#pragma unroll
          for (int i = 0; i < 8; ++i) {
            int idx = t + (i << 6);
            if (idx < DBLK)
              ok &= (__hip_atomic_load(&flags[idx], __ATOMIC_ACQUIRE, __HIP_MEMORY_SCOPE_AGENT) >= v);
          }
          if (__all(ok)) break;
          __builtin_amdgcn_s_sleep(2);
        }
        __threadfence();
      }
      // ---- P2: GRU step (gi via MFMA C-init; gates in-register) ----
      {
        const char* hbin = (const char*)((s & 1) ? hbY : hbX);
        unsigned short* hbout = (s & 1) ? hbX : hbY;
        int c0 = bid * 32;
        f32x16 aR, aZ, aN;
        float giN[16];
#pragma unroll
        for (int q = 0; q < 16; ++q) { aR[q] = 0.f; aZ[q] = 0.f; aN[q] = 0.f; giN[q] = 0.f; }
        for (int kcx = 0; kcx < DKC; ++kcx) {
          const float* pb = parts + (size_t)kcx * (DNT * 1024);
          const float* p0 = pb + (size_t)(0 * 16 + bid) * 1024 + b31;
          const float* p1 = pb + (size_t)(1 * 16 + bid) * 1024 + b31;
          const float* p2 = pb + (size_t)(2 * 16 + bid) * 1024 + b31;
#pragma unroll
          for (int q = 0; q < 16; ++q) {
            int br = (q & 3) + 8 * (q >> 2) + 4 * kg;
            aR[q] += p0[br * 32];
            aZ[q] += p1[br * 32];
            giN[q] += p2[br * 32];
          }
        }
        const char* w0 = (const char*)whhB + (size_t)(0 * 512 + c0 + b31) * 1024 + kg * 16;
        const char* w1 = (const char*)whhB + (size_t)(1 * 512 + c0 + b31) * 1024 + kg * 16;
        const char* w2 = (const char*)whhB + (size_t)(2 * 512 + c0 + b31) * 1024 + kg * 16;
#pragma unroll 8
        for (int kk = 0; kk < 32; ++kk) {
          short8 a = *(const short8*)(hbin + b31 * 1024 + kk * 32 + kg * 16);
          aR = __builtin_amdgcn_mfma_f32_32x32x16_bf16(a, *(const short8*)(w0 + kk * 32), aR, 0, 0, 0);
          aZ = __builtin_amdgcn_mfma_f32_32x32x16_bf16(a, *(const short8*)(w1 + kk * 32), aZ, 0, 0, 0);
          aN = __builtin_amdgcn_mfma_f32_32x32x16_bf16(a, *(const short8*)(w2 + kk * 32), aN, 0, 0, 0);
        }
        int d = c0 + b31;
#pragma unroll
        for (int q = 0; q < 16; ++q) {
          int br = (q & 3) + 8 * (q >> 2) + 4 * kg;
          float r = sigm(aR[q] + bihr + bhhr);
          float z = sigm(aZ[q] + bihz + bhhz);
          float nn = tanhf(giN[q] + bihn + r * (aN[q] + bhhn));
          float hnew = (1.f - z) * nn + z * hreg[q];
          hreg[q] = hnew;
          hbout[br * 512 + d] = f2bf(hnew);
        }
      }
      if (t == 0) {
        __threadfence();
        __hip_atomic_store(&flags[bid], 4 * s + 3, __ATOMIC_RELEASE, __HIP_MEMORY_SCOPE_AGENT);
      }
      // ---- wait: P2 done (flags[0..15] >= 4s+3) ----
      {
        int v = 4 * s + 3;
        for (;;) {
          int f = __hip_atomic_load(&flags[t & 15], __ATOMIC_ACQUIRE, __HIP_MEMORY_SCOPE_AGENT);
          if (__all(f >= v)) break;
          __builtin_amdgcn_s_sleep(1);
        }
        __threadfence();
      }
      // ---- P3: out = h_new . fcW^T + fcb  (32x32 MFMA tile) ----
      {
        const char* hbo = (const char*)((s & 1) ? hbX : hbY);
        int n0 = bid * 32;
        f32x16 ac;
#pragma unroll
        for (int q = 0; q < 16; ++q) ac[q] = 0.f;
        const char* fw = (const char*)fcWb + (size_t)(n0 + b31) * 1024 + kg * 16;
#pragma unroll 8
        for (int kk = 0; kk < 32; ++kk) {
          short8 a = *(const short8*)(hbo + b31 * 1024 + kk * 32 + kg * 16);
          ac = __builtin_amdgcn_mfma_f32_32x32x16_bf16(a, *(const short8*)(fw + kk * 32), ac, 0, 0, 0);
        }
        int n = n0 + b31;
        if (n < N_NODES) {
#pragma unroll
          for (int q = 0; q < 16; ++q) {
            int br = (q & 3) + 8 * (q >> 2) + 4 * kg;
            out[(size_t)br * (DSTEPS * N_NODES) + s * N_NODES + n] = ac[q] + fb;
          }
        }
      }
      if (t == 0) {
        __threadfence();
        __hip_atomic_store(&flags[bid], 4 * s + 4, __ATOMIC_RELEASE, __HIP_MEMORY_SCOPE_AGENT);
      }
    }

    if (bid < NB) {
      // ---- wait: P3 done (flags[0..15] >= 4s+4) ----
      {
        int v = 4 * s + 4;
        for (;;) {
          int f = __hip_atomic_load(&flags[t & 15], __ATOMIC_ACQUIRE, __HIP_MEMORY_SCOPE_AGENT);
          if (__all(f >= v)) break;
          __builtin_amdgcn_s_sleep(1);
        }
        __threadfence();
      }
      // ---- P4: aggregate out row -> E8 for next step ----
      {
        const float* srcrow = out + (size_t)bid * (DSTEPS * N_NODES) + s * N_NODES;
        for (int i = t; i < N_NODES; i += 64) orow_s[i] = srcrow[i];
        __syncthreads();
        for (int n = t; n < N_NODES; n += 64) {
          int e1 = rowptr[n + 1];
          float a = 0.f;
          for (int e = rowptr[n]; e < e1; ++e) a += nrmA[e] * orow_s[colA[e]];
          short8 lo, hi;
#pragma unroll
          for (int c = 0; c < 8; ++c) {
            lo[c] = (short)f2bf(fmaxf(a * wd16[c] + bd16[c], 0.f));
            hi[c] = (short)f2bf(fmaxf(a * wd16[c + 8] + bd16[c + 8], 0.f));
          }
          unsigned short* dst = E8 + (size_t)bid * NH + n * 16;
          *(short8*)dst = lo;
          *(short8*)(dst + 8) = hi;
        }
        __syncthreads();
      }
      if (t == 0) {
        __threadfence();
        __hip_atomic_store(&flags[bid], 4 * s + 5, __ATOMIC_RELEASE, __HIP_MEMORY_SCOPE_AGENT);
      }
    }
  }
}

extern "C" void kernel_launch(void* const* d_in, const int* in_sizes, int n_in,
                              void* d_out, int out_size, void* d_ws, size_t ws_size,
                              hipStream_t stream) {
  const float* x = (const float*)d_in[0];
  const float* dec0 = (const float*)d_in[1];
  const int* ei = (const int*)d_in[2];
  const float* gWe = (const float*)d_in[3];
  const float* gbe = (const float*)d_in[4];
  const float* gWd = (const float*)d_in[5];
  const float* gbd = (const float*)d_in[6];
  const float* eWih = (const float*)d_in[7];
  const float* eWhh = (const float*)d_in[8];
  const float* ebih = (const float*)d_in[9];
  const float* ebhh = (const float*)d_in[10];
  const float* dWih = (const float*)d_in[11];
  const float* dWhh = (const float*)d_in[12];
  const float* dbih = (const float*)d_in[13];
  const float* dbhh = (const float*)d_in[14];
  const float* fcW = (const float*)d_in[15];
  const float* fcb = (const float*)d_in[16];
  float* out = (float*)d_out;
  (void)in_sizes; (void)n_in; (void)out_size; (void)ws_size;

  char* w = (char*)d_ws;
  size_t off = 0;
  auto alloc = [&](size_t bytes) -> void* {
    void* p = w + off;
    off = (off + bytes + 255) & ~(size_t)255;
    return p;
  };
  int* deg = (int*)alloc(512 * 4);
  float* dinv = (float*)alloc(512 * 4);
  int* rowptr = (int*)alloc(512 * 4);
  int* cursor = (int*)alloc(512 * 4);
  int* colA = (int*)alloc(E_TOT * 4);
  float* nrmA = (float*)alloc(E_TOT * 4);
  unsigned short* whhE = (unsigned short*)alloc((size_t)G3 * DH * 2);
  unsigned short* whhD = (unsigned short*)alloc((size_t)G3 * DH * 2);
  unsigned short* AhatD = (unsigned short*)alloc(512 * 512 * 2);
  float* hF = (float*)alloc(NB * DH * 4);                     // | contiguous:
  unsigned short* hbX = (unsigned short*)alloc(NB * DH * 2);  // | one memset
  int* arr = (int*)alloc(256);                                // |
  int* dflags = (int*)alloc(2048);                            // |
  unsigned short* hbY = (unsigned short*)alloc(NB * DH * 2);
  unsigned short* E8 = (unsigned short*)alloc((size_t)NB * NH * 2);
  unsigned short* fcWb = (unsigned short*)alloc((size_t)512 * DH * 2);
  unsigned short* emb = (unsigned short*)alloc((size_t)BT * NH * 2);
  char* wihE_parts = (char*)alloc((size_t)G3 * NH * 2);   // wihE, later parts
  unsigned short* wihE = (unsigned short*)wihE_parts;
  float* parts = (float*)wihE_parts;
  unsigned short* wihDp = (unsigned short*)alloc((size_t)DBLK * 25600 * 2);
  char* xT2_giP = (char*)alloc((size_t)16384 * 512 * 2);  // xT2, later giP2
  unsigned short* xT2 = (unsigned short*)xT2_giP;
  float* giP2 = (float*)xT2_giP;

  // zero hF + hbX + arr + dflags (contiguous)
  hipMemsetAsync(hF, 0, NB * DH * 4 + NB * DH * 2 + 256 + 2048, stream);

  k_deg_init<<<2, 256, 0, stream>>>(deg);
  k_deg_count<<<(E_EDGES + 255) / 256, 256, 0, stream>>>(ei, deg);
  k_scan<<<1, 512, 0, stream>>>(deg, dinv, rowptr, cursor);
  k_scatter<<<(E_TOT + 255) / 256, 256, 0, stream>>>(ei, dinv, cursor, colA, nrmA);

  int n4w = G3 * NH / 4;
  int n4h = G3 * DH / 4;
  int n4f = N_NODES * DH / 4;
  k_f2bf4<<<(n4w + 255) / 256, 256, 0, stream>>>(eWih, wihE, n4w);
  k_f2bf4<<<(n4h + 255) / 256, 256, 0, stream>>>(eWhh, whhE, n4h);
  k_f2bf4<<<(n4h + 255) / 256, 256, 0, stream>>>(dWhh, whhD, n4h);
  k_f2bf4<<<(n4f + 255) / 256, 256, 0, stream>>>(fcW, fcWb, n4f);
  k_repack<<<3000, 256, 0, stream>>>(dWih, wihDp);

  k_transpose<<<BT, 256, 0, stream>>>(x, xT2);
  k_densify<<<512, 256, 0, stream>>>(rowptr, colA, nrmA, AhatD);
  k_gemm_agg<<<dim3(128, 4), 256, 0, stream>>>(xT2, AhatD, gWe, gbe, emb);

  k_gemm_enc<<<dim3(BT / 128, G3 / 64), 256, 0, stream>>>(emb, wihE, giP2);

  k_enc_scan<<<16, 256, 0, stream>>>(whhE, giP2, ebih, ebhh, hF, hbX, hbY, arr);

  k_dec_all2<<<DBLK, 64, 0, stream>>>(wihDp, whhD, gWd, gbd, dbih, dbhh, fcWb, fcb,
                                      rowptr, colA, nrmA, dec0, hF, hbX, hbY,
                                      E8, parts, out, dflags);
}

// Round 9
// 1819.640 us; speedup vs baseline: 9.0473x; 9.0473x over previous
//
#include <hip/hip_runtime.h>
#include <stdint.h>

typedef short short8 __attribute__((ext_vector_type(8)));
typedef float f32x4 __attribute__((ext_vector_type(4)));
typedef float f32x16 __attribute__((ext_vector_type(16)));

#define N_NODES 500
#define HGC 16
#define DH 512
#define T_STEPS 64
#define NB 32
#define F_IN 8
#define DSTEPS 16
#define E_EDGES 16000
#define E_TOT 16500
#define NH 8000          // N*HG
#define G3 1536          // 3*D
#define BT 2048          // B*T
#define DKC 10           // decoder K-split (800 K each = 50 nodes)
#define DNT 48           // decoder ntiles (32 cols each)
#define DBLK 480         // 48 x 10 blocks

__device__ __forceinline__ unsigned short f2bf(float x) {
  unsigned int u = __float_as_uint(x);
  u = (u + 0x7fffu + ((u >> 16) & 1u)) >> 16;
  return (unsigned short)u;
}

__device__ __forceinline__ void gl_lds16(const void* g, void* l) {
  __builtin_amdgcn_global_load_lds((const __attribute__((address_space(1))) void*)g,
                                   (__attribute__((address_space(3))) void*)l, 16, 0, 0);
}

__device__ __forceinline__ float sigm(float x) { return 1.f / (1.f + __expf(-x)); }

// ---------------- graph prep ----------------
__global__ void k_deg_init(int* deg) {
  int t = blockIdx.x * blockDim.x + threadIdx.x;
  if (t < N_NODES) deg[t] = 1;  // self loop
}

__global__ void k_deg_count(const int* __restrict__ ei, int* deg) {
  int t = blockIdx.x * blockDim.x + threadIdx.x;
  if (t < E_EDGES) atomicAdd(&deg[ei[E_EDGES + t]], 1);
}

__global__ void k_scan(const int* __restrict__ deg, float* dinv, int* rowptr, int* cursor) {
  __shared__ int s[512];
  int t = threadIdx.x;
  int v = (t < N_NODES) ? deg[t] : 0;
  s[t] = v;
  __syncthreads();
  for (int off = 1; off < 512; off <<= 1) {
    int add = (t >= off) ? s[t - off] : 0;
    __syncthreads();
    s[t] += add;
    __syncthreads();
  }
  if (t < N_NODES) {
    int excl = s[t] - v;
    rowptr[t] = excl;
    cursor[t] = excl;
    dinv[t] = rsqrtf((float)v);
  }
  if (t == 0) rowptr[N_NODES] = s[511];
}

__global__ void k_scatter(const int* __restrict__ ei, const float* __restrict__ dinv,
                          int* cursor, int* col, float* nrm) {
  int t = blockIdx.x * blockDim.x + threadIdx.x;
  if (t >= E_TOT) return;
  int s_, d_;
  if (t < E_EDGES) { s_ = ei[t]; d_ = ei[E_EDGES + t]; }
  else { s_ = d_ = t - E_EDGES; }
  int pos = atomicAdd(&cursor[d_], 1);
  col[pos] = s_;
  nrm[pos] = dinv[s_] * dinv[d_];
}

// ---------------- f32 -> bf16 bulk convert ----------------
__global__ void k_f2bf4(const float* __restrict__ src, unsigned short* __restrict__ dst, int n4) {
  int i = blockIdx.x * blockDim.x + threadIdx.x;
  if (i >= n4) return;
  float4 v = ((const float4*)src)[i];
  ushort4 o;
  o.x = f2bf(v.x); o.y = f2bf(v.y); o.z = f2bf(v.z); o.w = f2bf(v.w);
  ((ushort4*)dst)[i] = o;
}

// ---------------- repack dWih f32 -> per-block blobs (bf16), layout [nd][kg][col][8] ----------------
__global__ __launch_bounds__(256) void k_repack(const float* __restrict__ dWih,
                                                unsigned short* __restrict__ wihDp) {
  int i = blockIdx.x * 256 + threadIdx.x;   // 768000 total
  if (i >= DBLK * 50 * 32) return;
  int blob = i / 1600, r = i - blob * 1600;
  int nd = r >> 5, col = r & 31;
  int ntile = blob / DKC, kc = blob - ntile * DKC;
  const float* src = dWih + (size_t)(ntile * 32 + col) * NH + kc * 800 + nd * 16;
  short8 lo, hi;
#pragma unroll
  for (int c = 0; c < 8; ++c) {
    lo[c] = (short)f2bf(src[c]);
    hi[c] = (short)f2bf(src[c + 8]);
  }
  unsigned short* dst = wihDp + (size_t)blob * 25600 + nd * 512 + col * 8;
  *(short8*)dst = lo;
  *(short8*)(dst + 256) = hi;
}

// ---------------- x (2048,500,8) f32 -> xT2 (16384, 512) bf16 (zero-padded cols) ----------------
__global__ __launch_bounds__(256) void k_transpose(const float* __restrict__ x,
                                                   unsigned short* __restrict__ xT2) {
  __shared__ float xs[N_NODES * 9];
  int g = blockIdx.x, t = threadIdx.x;
  const float4* xg = (const float4*)(x + (size_t)g * (N_NODES * F_IN));
  for (int i = t; i < N_NODES * 2; i += 256) {
    float4 v = xg[i];
    int n = i >> 1, fh = (i & 1) * 4;
    float* d = &xs[n * 9 + fh];
    d[0] = v.x; d[1] = v.y; d[2] = v.z; d[3] = v.w;
  }
  __syncthreads();
  int f = t >> 5, u = t & 31;
  short8 lo, hi;
#pragma unroll
  for (int j = 0; j < 8; ++j) {
    int n0 = u * 16 + j, n1 = n0 + 8;
    lo[j] = (short)((n0 < N_NODES) ? f2bf(xs[n0 * 9 + f]) : 0);
    hi[j] = (short)((n1 < N_NODES) ? f2bf(xs[n1 * 9 + f]) : 0);
  }
  unsigned short* dst = xT2 + (size_t)(g * 8 + f) * 512 + u * 16;
  *(short8*)dst = lo;
  *(short8*)(dst + 8) = hi;
}

// ---------------- densify Ahat rows (by dst) -> (512, 512) bf16 ----------------
__global__ __launch_bounds__(256) void k_densify(const int* __restrict__ rowptr,
                                                 const int* __restrict__ col,
                                                 const float* __restrict__ nrm,
                                                 unsigned short* __restrict__ AhatD) {
  __shared__ float row[512];
  int n = blockIdx.x, t = threadIdx.x;
  row[t] = 0.f; row[t + 256] = 0.f;
  __syncthreads();
  if (n < N_NODES) {
    int e1 = rowptr[n + 1];
    for (int e = rowptr[n] + t; e < e1; e += 256) atomicAdd(&row[col[e]], nrm[e]);
  }
  __syncthreads();
  AhatD[n * 512 + t] = f2bf(row[t]);
  AhatD[n * 512 + t + 256] = f2bf(row[t + 256]);
}

// ---------------- agg GEMM: C(16384 gf, 512 n) = xT2 . AhatD^T ; fused W(8->16)+relu -> emb ----------------
__global__ __launch_bounds__(256) void k_gemm_agg(const unsigned short* __restrict__ A,
                                                  const unsigned short* __restrict__ B,
                                                  const float* __restrict__ W,
                                                  const float* __restrict__ bias,
                                                  unsigned short* __restrict__ emb) {
  __shared__ float smem[64 * 129];
  __shared__ float Wsm[F_IN * HGC];
  __shared__ float bsm[HGC];
  unsigned short* As = (unsigned short*)smem;
  unsigned short* Bs = As + 4096;
  int t = threadIdx.x;
  if (t < F_IN * HGC) Wsm[t] = W[t];
  if (t < HGC) bsm[t] = bias[t];
  int m0 = blockIdx.x * 128, n0 = blockIdx.y * 128;
  int wave = t >> 6, lane = t & 63;
  int mh = (wave >> 1) * 64, nh = (wave & 1) * 64;
  int lrow = t >> 2, lslot = t & 3;
  f32x4 acc[4][4];
#pragma unroll
  for (int a = 0; a < 4; ++a)
#pragma unroll
    for (int b = 0; b < 4; ++b) acc[a][b] = (f32x4){0.f, 0.f, 0.f, 0.f};
  const unsigned short* ga0 = A + (size_t)(m0 + lrow) * 512 + lslot * 8;
  const unsigned short* ga1 = A + (size_t)(m0 + 64 + lrow) * 512 + lslot * 8;
  const unsigned short* gb0 = B + (size_t)(n0 + lrow) * 512 + lslot * 8;
  const unsigned short* gb1 = B + (size_t)(n0 + 64 + lrow) * 512 + lslot * 8;
  int rl = lane & 15, ks = lane >> 4;
  for (int kt = 0; kt < 16; ++kt) {
    int k0 = kt * 32;
    gl_lds16(ga0 + k0, &As[t * 8]);
    gl_lds16(ga1 + k0, &As[2048 + t * 8]);
    gl_lds16(gb0 + k0, &Bs[t * 8]);
    gl_lds16(gb1 + k0, &Bs[2048 + t * 8]);
    __syncthreads();
    short8 af[4], bfr[4];
#pragma unroll
    for (int mf = 0; mf < 4; ++mf) af[mf] = *(const short8*)&As[(mh + mf * 16 + rl) * 32 + ks * 8];
#pragma unroll
    for (int nf = 0; nf < 4; ++nf) bfr[nf] = *(const short8*)&Bs[(nh + nf * 16 + rl) * 32 + ks * 8];
#pragma unroll
    for (int mf = 0; mf < 4; ++mf)
#pragma unroll
      for (int nf = 0; nf < 4; ++nf)
        acc[mf][nf] = __builtin_amdgcn_mfma_f32_16x16x32_bf16(af[mf], bfr[nf], acc[mf][nf], 0, 0, 0);
    __syncthreads();
  }
  int rg = lane >> 4;
  for (int p = 0; p < 2; ++p) {
    if ((wave >> 1) == p) {
#pragma unroll
      for (int mf = 0; mf < 4; ++mf)
#pragma unroll
        for (int nf = 0; nf < 4; ++nf)
#pragma unroll
          for (int q = 0; q < 4; ++q)
            smem[(mf * 16 + rg * 4 + q) * 129 + nh + nf * 16 + rl] = acc[mf][nf][q];
    }
    __syncthreads();
    int gl = t >> 5, sub = t & 31;
    int g = blockIdx.x * 16 + p * 8 + gl;
#pragma unroll
    for (int j = 0; j < 4; ++j) {
      int nl = sub + 32 * j, ng = n0 + nl;
      if (ng < N_NODES) {
        float v[8];
#pragma unroll
        for (int f = 0; f < 8; ++f) v[f] = smem[(gl * 8 + f) * 129 + nl];
        short8 o0, o1;
#pragma unroll
        for (int c = 0; c < 8; ++c) {
          float s0 = bsm[c], s1 = bsm[c + 8];
#pragma unroll
          for (int f = 0; f < 8; ++f) {
            s0 += v[f] * Wsm[f * 16 + c];
            s1 += v[f] * Wsm[f * 16 + c + 8];
          }
          o0[c] = (short)f2bf(fmaxf(s0, 0.f));
          o1[c] = (short)f2bf(fmaxf(s1, 0.f));
        }
        unsigned short* dst = emb + (size_t)g * NH + ng * 16;
        *(short8*)dst = o0;
        *(short8*)(dst + 8) = o1;
      }
    }
    __syncthreads();
  }
}

// ---------------- big encoder GEMM: gi = emb(2048x8000) . Wih(1536x8000)^T ----------------
__global__ __launch_bounds__(256) void k_gemm_enc(
    const unsigned short* __restrict__ A, const unsigned short* __restrict__ Bm,
    float* __restrict__ giP2) {
  __shared__ unsigned short As[128 * 32];
  __shared__ unsigned short Bs[64 * 32];
  int t = threadIdx.x;
  int m0 = blockIdx.x * 128, n0 = blockIdx.y * 64;
  int wave = t >> 6, lane = t & 63;
  int mh = (wave >> 1) * 64, nh = (wave & 1) * 32;
  int lrow = t >> 2, lslot = t & 3;
  f32x4 acc[4][2];
#pragma unroll
  for (int a = 0; a < 4; ++a)
#pragma unroll
    for (int b = 0; b < 2; ++b) acc[a][b] = (f32x4){0.f, 0.f, 0.f, 0.f};
  const unsigned short* ga0 = A + (size_t)(m0 + lrow) * NH + lslot * 8;
  const unsigned short* ga1 = A + (size_t)(m0 + 64 + lrow) * NH + lslot * 8;
  const unsigned short* gb0 = Bm + (size_t)(n0 + lrow) * NH + lslot * 8;
  int rl = lane & 15, ks = lane >> 4;
  for (int kt = 0; kt < 250; ++kt) {
    int k0 = kt * 32;
    gl_lds16(ga0 + k0, &As[t * 8]);
    gl_lds16(ga1 + k0, &As[2048 + t * 8]);
    gl_lds16(gb0 + k0, &Bs[t * 8]);
    __syncthreads();
    short8 af[4], bfr[2];
#pragma unroll
    for (int mf = 0; mf < 4; ++mf) af[mf] = *(const short8*)&As[(mh + mf * 16 + rl) * 32 + ks * 8];
#pragma unroll
    for (int nf = 0; nf < 2; ++nf) bfr[nf] = *(const short8*)&Bs[(nh + nf * 16 + rl) * 32 + ks * 8];
#pragma unroll
    for (int mf = 0; mf < 4; ++mf)
#pragma unroll
      for (int nf = 0; nf < 2; ++nf)
        acc[mf][nf] = __builtin_amdgcn_mfma_f32_16x16x32_bf16(af[mf], bfr[nf], acc[mf][nf], 0, 0, 0);
    __syncthreads();
  }
  int rg = lane >> 4;
  int gate = n0 >> 9;
#pragma unroll
  for (int mf = 0; mf < 4; ++mf)
#pragma unroll
    for (int nf = 0; nf < 2; ++nf) {
      int n = n0 + nh + nf * 16 + rl;
      int d = n & 511, blk = d >> 5, cc = d & 31;
#pragma unroll
      for (int q = 0; q < 4; ++q) {
        int m = m0 + mh + mf * 16 + rg * 4 + q;
        int s = m & 63, bb = m >> 6;
        giP2[(size_t)(s * 16 + blk) * 3072 + gate * 1024 + bb * 32 + cc] = acc[mf][nf][q];
      }
    }
}

// ---------------- stage h into XOR-swizzled LDS ----------------
__device__ __forceinline__ void stage_hb(const unsigned short* __restrict__ src,
                                         unsigned short* hb, int t) {
  int bw = t >> 3, i8 = t & 7;
  short8 v[8];
#pragma unroll
  for (int i = 0; i < 8; ++i)
    v[i] = *(const short8*)((const char*)src + bw * 1024 + i8 * 128 + i * 16);
#pragma unroll
  for (int i = 0; i < 8; ++i) {
    int kb = i8 * 128 + i * 16;
    *(short8*)((char*)hb + bw * 1024 + (kb ^ ((bw & 15) << 4))) = v[i];
  }
}

__device__ __forceinline__ void gru_core_g(const unsigned short* __restrict__ whhB,
                                           const unsigned short* hb, float* gh,
                                           int t, int c0) {
  int lane = t & 63, g = t >> 6;
  int b31 = lane & 31, kg = lane >> 5;
  if (g < 3) {
    f32x16 acc;
#pragma unroll
    for (int q = 0; q < 16; ++q) acc[q] = 0.f;
    const unsigned short* brow = whhB + (size_t)(g * 512 + c0 + b31) * 512 + kg * 8;
    int asw = (b31 & 15) << 4;
#pragma unroll 4
    for (int kk = 0; kk < 32; ++kk) {
      int kb = (kk * 32 + kg * 16) ^ asw;
      short8 a = *(const short8*)((const char*)hb + b31 * 1024 + kb);
      short8 b = *(const short8*)(brow + kk * 16);
      acc = __builtin_amdgcn_mfma_f32_32x32x16_bf16(a, b, acc, 0, 0, 0);
    }
#pragma unroll
    for (int q = 0; q < 16; ++q) {
      int br = (q & 3) + 8 * (q >> 2) + 4 * kg;
      gh[g * 1024 + br * 32 + b31] = acc[q];
    }
  }
}

__device__ __forceinline__ void gru_gates(const float* gi, const float* gh,
                                          const float* __restrict__ bih,
                                          const float* __restrict__ bhh,
                                          float* __restrict__ hF,
                                          unsigned short* __restrict__ hb_out,
                                          int t, int c0) {
  for (int i = t; i < 1024; i += 256) {
    int b = i >> 5, cc = i & 31, d = c0 + cc;
    float gr = gi[i] + bih[d];
    float gz = gi[1024 + i] + bih[512 + d];
    float gn = gi[2048 + i] + bih[1024 + d];
    float hr = gh[b * 32 + cc] + bhh[d];
    float hz = gh[1024 + b * 32 + cc] + bhh[512 + d];
    float hn = gh[2048 + b * 32 + cc] + bhh[1024 + d];
    float r = sigm(gr + hr), z = sigm(gz + hz);
    float nn = tanhf(gn + r * hn);
    float hp = hF[b * 512 + d];
    float hnew = (1.f - z) * nn + z * hp;
    hF[b * 512 + d] = hnew;
    hb_out[b * 512 + d] = f2bf(hnew);
  }
}

// ---------------- persistent encoder scan (R5 structure, measured 341us) ----------------
__global__ __launch_bounds__(256, 1) void k_enc_scan(
    const unsigned short* __restrict__ whhB, const float* __restrict__ giP2,
    const float* __restrict__ bih, const float* __restrict__ bhh,
    float* __restrict__ hF, unsigned short* __restrict__ hbA,
    unsigned short* __restrict__ hbB, int* __restrict__ arr) {
  __shared__ unsigned short hb[32 * 512];
  __shared__ float gh[3 * 1024];
  __shared__ float h32[1024];
  __shared__ float gi_lds[3072];
  int t = threadIdx.x, bid = blockIdx.x;
  int c0 = bid * 32;
  int lane = t & 63, g = t >> 6;
  int b31 = lane & 31, kg = lane >> 5;

  short8 wreg[32];
  if (g < 3) {
    const unsigned short* brow = whhB + (size_t)(g * 512 + c0 + b31) * 512 + kg * 8;
#pragma unroll
    for (int kk = 0; kk < 32; ++kk) wreg[kk] = *(const short8*)(brow + kk * 16);
  }
  for (int i = t; i < 1024; i += 256) h32[i] = 0.f;
  int cc = t & 31, d = c0 + cc;
  float bi_r = bih[d], bi_z = bih[512 + d], bi_n = bih[1024 + d];
  float bh_r = bhh[d], bh_z = bhh[512 + d], bh_n = bhh[1024 + d];
  int asw = (b31 & 15) << 4;
  {
    const float* src0 = giP2 + (size_t)bid * 3072;
#pragma unroll
    for (int i = 0; i < 3; ++i)
      gl_lds16(src0 + i * 1024 + t * 4, &gi_lds[i * 1024 + t * 4]);
  }
  __syncthreads();

  for (int s = 0; s < T_STEPS; ++s) {
    const unsigned short* hbin = (s & 1) ? hbB : hbA;
    unsigned short* hbout = (s & 1) ? hbA : hbB;
    if (s > 0 && t < 64) {
      for (;;) {
        int v = __hip_atomic_load(&arr[t & 15], __ATOMIC_ACQUIRE, __HIP_MEMORY_SCOPE_AGENT);
        if (__all(v >= s)) break;
        __builtin_amdgcn_s_sleep(1);
      }
    }
    __syncthreads();
    stage_hb(hbin, hb, t);
    __syncthreads();
    if (g < 3) {
      f32x16 acc0, acc1;
#pragma unroll
      for (int q = 0; q < 16; ++q) { acc0[q] = 0.f; acc1[q] = 0.f; }
      const char* abase = (const char*)hb + b31 * 1024;
#pragma unroll
      for (int kk = 0; kk < 32; ++kk) {
        int kb = (kk * 32 + kg * 16) ^ asw;
        short8 a = *(const short8*)(abase + kb);
        if (kk & 1) acc1 = __builtin_amdgcn_mfma_f32_32x32x16_bf16(a, wreg[kk], acc1, 0, 0, 0);
        else acc0 = __builtin_amdgcn_mfma_f32_32x32x16_bf16(a, wreg[kk], acc0, 0, 0, 0);
      }
#pragma unroll
      for (int q = 0; q < 16; ++q) {
        int br = (q & 3) + 8 * (q >> 2) + 4 * kg;
        gh[g * 1024 + br * 32 + b31] = acc0[q] + acc1[q];
      }
    }
    __syncthreads();
#pragma unroll
    for (int j = 0; j < 4; ++j) {
      int i = t + 256 * j;
      int b = (t >> 5) + 8 * j;
      float r = sigm(gi_lds[i] + bi_r + gh[i] + bh_r);
      float z = sigm(gi_lds[1024 + i] + bi_z + gh[1024 + i] + bh_z);
      float nn = tanhf(gi_lds[2048 + i] + bi_n + r * (gh[2048 + i] + bh_n));
      float hnew = (1.f - z) * nn + z * h32[i];
      h32[i] = hnew;
      hbout[b * 512 + d] = f2bf(hnew);
    }
    __syncthreads();
    if (g == 3 && s + 1 < T_STEPS) {
      const float* srcn = giP2 + (size_t)((s + 1) * 16 + bid) * 3072;
#pragma unroll
      for (int i = 0; i < 12; ++i)
        gl_lds16(srcn + (i * 64 + lane) * 4, &gi_lds[(i * 64 + lane) * 4]);
    }
    if (t == 0) {
      __threadfence();
      __hip_atomic_store(&arr[bid], s + 1, __ATOMIC_RELEASE, __HIP_MEMORY_SCOPE_AGENT);
    }
  }
#pragma unroll
  for (int j = 0; j < 4; ++j) {
    int i = t + 256 * j;
    int b = (t >> 5) + 8 * j;
    hF[b * 512 + d] = h32[i];
  }
}

// ---------------- decoder gi GEMM v3: LDS-staged weights, pure MFMA ----------------
// 480 blocks x 64 threads. parts[(kc*48+ntile)*1024 + batch*32 + col]
__global__ __launch_bounds__(64) void k_dec_gemm(
    const unsigned short* __restrict__ wihDp, const unsigned short* __restrict__ E8,
    float* __restrict__ parts) {
  __shared__ unsigned short wlds[25600];  // [50 nd][2 kg][32 col][8 c] = 51.2 KB
  int bid = blockIdx.x, t = threadIdx.x;
  int b31 = t & 31, kg = t >> 5;
  int ntile = bid / DKC, kc = bid - ntile * DKC;
  const unsigned short* src = wihDp + (size_t)bid * 25600;
#pragma unroll 10
  for (int i = 0; i < 50; ++i)
    gl_lds16(src + i * 512 + t * 8, (char*)wlds + i * 1024 + t * 16);
  __syncthreads();  // one vmcnt drain for all 50 staging loads
  f32x16 acc0, acc1;
#pragma unroll
  for (int q = 0; q < 16; ++q) { acc0[q] = 0.f; acc1[q] = 0.f; }
  const unsigned short* ea = E8 + (size_t)b31 * NH + kc * 800 + kg * 8;
  const char* wb = (const char*)wlds + kg * 512 + b31 * 16;
#pragma unroll 5
  for (int nd = 0; nd < 50; nd += 2) {
    short8 a0 = *(const short8*)(ea + nd * 16);
    short8 b0 = *(const short8*)(wb + (size_t)nd * 1024);
    short8 a1 = *(const short8*)(ea + (nd + 1) * 16);
    short8 b1 = *(const short8*)(wb + (size_t)(nd + 1) * 1024);
    acc0 = __builtin_amdgcn_mfma_f32_32x32x16_bf16(a0, b0, acc0, 0, 0, 0);
    acc1 = __builtin_amdgcn_mfma_f32_32x32x16_bf16(a1, b1, acc1, 0, 0, 0);
  }
  float* pp = parts + (size_t)(kc * DNT + ntile) * 1024 + b31;
#pragma unroll
  for (int q = 0; q < 16; ++q) {
    int br = (q & 3) + 8 * (q >> 2) + 4 * kg;
    pp[br * 32] = acc0[q] + acc1[q];
  }
}

// ---------------- decoder GRU step (16 blocks x 256) ----------------
__global__ __launch_bounds__(256) void k_gru_dec(
    const unsigned short* __restrict__ whhB, const float* __restrict__ parts,
    const float* __restrict__ bih, const float* __restrict__ bhh,
    float* hF, const unsigned short* __restrict__ hb_in, unsigned short* __restrict__ hb_out) {
  __shared__ unsigned short hb[32 * 512];
  __shared__ float gh[3 * 32 * 32];
  __shared__ float gi[3 * 32 * 32];
  int t = threadIdx.x;
  int bid = blockIdx.x;
  int c0 = bid * 32;
  stage_hb(hb_in, hb, t);
  for (int i = t; i < 3072; i += 256) {
    int gg = i >> 10, r = i & 1023, bb = r >> 5, cc2 = r & 31;
    float a = 0.f;
#pragma unroll
    for (int kc = 0; kc < DKC; ++kc)
      a += parts[((size_t)kc * DNT + gg * 16 + bid) * 1024 + bb * 32 + cc2];
    gi[i] = a;
  }
  __syncthreads();
  gru_core_g(whhB, hb, gh, t, c0);
  __syncthreads();
  gru_gates(gi, gh, bih, bhh, hF, hb_out, t, c0);
}

// ---------------- fc + out + E8 emission for next step (32 blocks x 256) ----------------
__global__ __launch_bounds__(256) void k_fc_agg(
    const float* __restrict__ hF, const float* __restrict__ fcW, const float* __restrict__ fcb,
    const float* __restrict__ Wd, const float* __restrict__ bd,
    const int* __restrict__ rowptr, const int* __restrict__ col, const float* __restrict__ nrm,
    float* __restrict__ out, unsigned short* __restrict__ E8, int s) {
  __shared__ float hrow[512];
  __shared__ float orow[N_NODES];
  __shared__ float wds[HGC], bds[HGC];
  int b = blockIdx.x, t = threadIdx.x;
  hrow[t] = hF[b * 512 + t];
  hrow[t + 256] = hF[b * 512 + t + 256];
  if (t < HGC) { wds[t] = Wd[t]; bds[t] = bd[t]; }
  __syncthreads();
  for (int n = t; n < N_NODES; n += 256) {
    const float4* wr = (const float4*)(fcW + (size_t)n * DH);
    float a = 0.f;
#pragma unroll 4
    for (int k = 0; k < 128; ++k) {
      float4 wv = wr[k];
      const float4 hv = *(const float4*)&hrow[k * 4];
      a += wv.x * hv.x + wv.y * hv.y + wv.z * hv.z + wv.w * hv.w;
    }
    float o = a + fcb[n];
    orow[n] = o;
    out[(size_t)b * (DSTEPS * N_NODES) + s * N_NODES + n] = o;
  }
  __syncthreads();
  for (int n = t; n < N_NODES; n += 256) {
    int e1 = rowptr[n + 1];
    float a = 0.f;
    for (int e = rowptr[n]; e < e1; ++e) a += nrm[e] * orow[col[e]];
    short8 lo, hi;
#pragma unroll
    for (int c = 0; c < 8; ++c) {
      lo[c] = (short)f2bf(fmaxf(a * wds[c] + bds[c], 0.f));
      hi[c] = (short)f2bf(fmaxf(a * wds[c + 8] + bds[c + 8], 0.f));
    }
    unsigned short* dst = E8 + (size_t)b * NH + n * 16;
    *(short8*)dst = lo;
    *(short8*)(dst + 8) = hi;
  }
}

// ---------------- initial E8 from decoder_initial_input ----------------
__global__ __launch_bounds__(256) void k_agg0(
    const float* __restrict__ dec0, const float* __restrict__ Wd, const float* __restrict__ bd,
    const int* __restrict__ rowptr, const int* __restrict__ col, const float* __restrict__ nrm,
    unsigned short* __restrict__ E8) {
  __shared__ float irow[N_NODES];
  __shared__ float wds[HGC], bds[HGC];
  int b = blockIdx.x, t = threadIdx.x;
  for (int n = t; n < N_NODES; n += 256) irow[n] = dec0[b * N_NODES + n];
  if (t < HGC) { wds[t] = Wd[t]; bds[t] = bd[t]; }
  __syncthreads();
  for (int n = t; n < N_NODES; n += 256) {
    int e1 = rowptr[n + 1];
    float a = 0.f;
    for (int e = rowptr[n]; e < e1; ++e) a += nrm[e] * irow[col[e]];
    short8 lo, hi;
#pragma unroll
    for (int c = 0; c < 8; ++c) {
      lo[c] = (short)f2bf(fmaxf(a * wds[c] + bds[c], 0.f));
      hi[c] = (short)f2bf(fmaxf(a * wds[c + 8] + bds[c + 8], 0.f));
    }
    unsigned short* dst = E8 + (size_t)b * NH + n * 16;
    *(short8*)dst = lo;
    *(short8*)(dst + 8) = hi;
  }
}

extern "C" void kernel_launch(void* const* d_in, const int* in_sizes, int n_in,
                              void* d_out, int out_size, void* d_ws, size_t ws_size,
                              hipStream_t stream) {
  const float* x = (const float*)d_in[0];
  const float* dec0 = (const float*)d_in[1];
  const int* ei = (const int*)d_in[2];
  const float* gWe = (const float*)d_in[3];
  const float* gbe = (const float*)d_in[4];
  const float* gWd = (const float*)d_in[5];
  const float* gbd = (const float*)d_in[6];
  const float* eWih = (const float*)d_in[7];
  const float* eWhh = (const float*)d_in[8];
  const float* ebih = (const float*)d_in[9];
  const float* ebhh = (const float*)d_in[10];
  const float* dWih = (const float*)d_in[11];
  const float* dWhh = (const float*)d_in[12];
  const float* dbih = (const float*)d_in[13];
  const float* dbhh = (const float*)d_in[14];
  const float* fcW = (const float*)d_in[15];
  const float* fcb = (const float*)d_in[16];
  float* out = (float*)d_out;
  (void)in_sizes; (void)n_in; (void)out_size; (void)ws_size;

  char* w = (char*)d_ws;
  size_t off = 0;
  auto alloc = [&](size_t bytes) -> void* {
    void* p = w + off;
    off = (off + bytes + 255) & ~(size_t)255;
    return p;
  };
  int* deg = (int*)alloc(512 * 4);
  float* dinv = (float*)alloc(512 * 4);
  int* rowptr = (int*)alloc(512 * 4);
  int* cursor = (int*)alloc(512 * 4);
  int* colA = (int*)alloc(E_TOT * 4);
  float* nrmA = (float*)alloc(E_TOT * 4);
  unsigned short* whhE = (unsigned short*)alloc((size_t)G3 * DH * 2);
  unsigned short* whhD = (unsigned short*)alloc((size_t)G3 * DH * 2);
  unsigned short* AhatD = (unsigned short*)alloc(512 * 512 * 2);
  float* hF = (float*)alloc(NB * DH * 4);                     // | contiguous:
  unsigned short* hbX = (unsigned short*)alloc(NB * DH * 2);  // | one memset
  int* arr = (int*)alloc(256);                                // |
  unsigned short* hbY = (unsigned short*)alloc(NB * DH * 2);
  unsigned short* E8 = (unsigned short*)alloc((size_t)NB * NH * 2);
  unsigned short* emb = (unsigned short*)alloc((size_t)BT * NH * 2);
  char* wihE_parts = (char*)alloc((size_t)G3 * NH * 2);   // wihE, later parts
  unsigned short* wihE = (unsigned short*)wihE_parts;
  float* parts = (float*)wihE_parts;
  unsigned short* wihDp = (unsigned short*)alloc((size_t)DBLK * 25600 * 2);
  char* xT2_giP = (char*)alloc((size_t)16384 * 512 * 2);  // xT2, later giP2
  unsigned short* xT2 = (unsigned short*)xT2_giP;
  float* giP2 = (float*)xT2_giP;

  // zero hF + hbX + arr (contiguous)
  hipMemsetAsync(hF, 0, NB * DH * 4 + NB * DH * 2 + 256, stream);

  k_deg_init<<<2, 256, 0, stream>>>(deg);
  k_deg_count<<<(E_EDGES + 255) / 256, 256, 0, stream>>>(ei, deg);
  k_scan<<<1, 512, 0, stream>>>(deg, dinv, rowptr, cursor);
  k_scatter<<<(E_TOT + 255) / 256, 256, 0, stream>>>(ei, dinv, cursor, colA, nrmA);

  int n4w = G3 * NH / 4;
  int n4h = G3 * DH / 4;
  k_f2bf4<<<(n4w + 255) / 256, 256, 0, stream>>>(eWih, wihE, n4w);
  k_f2bf4<<<(n4h + 255) / 256, 256, 0, stream>>>(eWhh, whhE, n4h);
  k_f2bf4<<<(n4h + 255) / 256, 256, 0, stream>>>(dWhh, whhD, n4h);
  k_repack<<<3000, 256, 0, stream>>>(dWih, wihDp);

  k_transpose<<<BT, 256, 0, stream>>>(x, xT2);
  k_densify<<<512, 256, 0, stream>>>(rowptr, colA, nrmA, AhatD);
  k_gemm_agg<<<dim3(128, 4), 256, 0, stream>>>(xT2, AhatD, gWe, gbe, emb);

  k_gemm_enc<<<dim3(BT / 128, G3 / 64), 256, 0, stream>>>(emb, wihE, giP2);

  k_enc_scan<<<16, 256, 0, stream>>>(whhE, giP2, ebih, ebhh, hF, hbX, hbY, arr);

  k_agg0<<<NB, 256, 0, stream>>>(dec0, gWd, gbd, rowptr, colA, nrmA, E8);

  for (int s = 0; s < DSTEPS; ++s) {
    const unsigned short* hbin = (s & 1) ? hbY : hbX;
    unsigned short* hbout = (s & 1) ? hbX : hbY;
    k_dec_gemm<<<DBLK, 64, 0, stream>>>(wihDp, E8, parts);
    k_gru_dec<<<16, 256, 0, stream>>>(whhD, parts, dbih, dbhh, hF, hbin, hbout);
    k_fc_agg<<<NB, 256, 0, stream>>>(hF, fcW, fcb, gWd, gbd, rowptr, colA, nrmA, out, E8, s);
  }
}